// Round 10
// baseline (278.698 us; speedup 1.0000x reference)
//
#include <hip/hip_runtime.h>
#include <cstdint>
#include <cstddef>

// ---------------------------------------------------------------------------
// TransformerLayer forward on MI355X (gfx950), bf16 MFMA pipeline.
// B=2, S=2048, D=1024, H=16, HD=64.  M = B*S = 4096 rows.
// Round 10: uniform single-barrier counted-prefetch loop (T3-minimum recipe)
// in all three MFMA kernels: { stage(next); WAITVM(n); compute(cur);
// s_barrier; } — one barrier per K-step (was two), stage issued BEFORE
// compute. Buffering/occupancy unchanged (isolates barrier frequency).
// ---------------------------------------------------------------------------

#define B_ 2
#define S_ 2048
#define D_ 1024
#define H_ 16
#define M_ 4096

typedef __attribute__((ext_vector_type(4))) float  f32x4;
typedef __attribute__((ext_vector_type(8))) __bf16 bf16x8;
typedef __attribute__((ext_vector_type(4))) __bf16 bf16x4;

#define WAITVM(N) asm volatile("s_waitcnt vmcnt(" #N ")" ::: "memory")

__device__ __forceinline__ void async16(const void* g, void* l) {
    __builtin_amdgcn_global_load_lds(
        (__attribute__((address_space(1))) void*)(g),
        (__attribute__((address_space(3))) void*)(l), 16, 0, 0);
}

// sigmoid(z)*tanh(z) == (1-u)/(1+u^2), u = exp(-z), z = s/32.
__device__ __forceinline__ float actf(float s) {
    float t = fminf(s * -0.045084223f, 21.6f);
    float u = __builtin_amdgcn_exp2f(t);
    return (1.f - u) * __builtin_amdgcn_rcpf(1.f + u * u);
}

// ---------------------------------------------------------------------------
// GEMM (N=1024 path): C[M][1024] = epi(A @ Bt^T + bias).  Tile 128x64,
// 4 waves x (64x32), 48 KB LDS dbuf, n-minor mapping, lb(256,3).
// Single-barrier loop: stage(next buf); WAITVM(6); compute(cur); barrier.
// EPI: 0 bias->bf16 | 1 leaky(0.2)->bf16 | 2 aux+s*(.)->bf16 | 3 aux+s*(.)->f32
// ---------------------------------------------------------------------------
template <int EPI, int NT>
__global__ __launch_bounds__(256, 3) void gemm_k(
    const __bf16* __restrict__ A, const __bf16* __restrict__ Bt,
    const float* __restrict__ bias, const __bf16* __restrict__ aux,
    const float* __restrict__ scal, void* __restrict__ out)
{
    constexpr int K = D_;
    constexpr int Ntot = NT * 64;
    __shared__ __align__(16) __bf16 As[2][128][64];  // 32 KB
    __shared__ __align__(16) __bf16 Bs[2][64][64];   // 16 KB

    const int tid = threadIdx.x, lane = tid & 63, wid = tid >> 6;
    const int wr = wid >> 1, wc = wid & 1;
    const int cpx = (int)gridDim.x >> 3;
    const int bid = (int)blockIdx.x;
    const int wg = (bid & 7) * cpx + (bid >> 3);    // XCD-bijective swizzle
    const int m0 = (wg / NT) * 128;                 // n-minor: A shared in chunk
    const int n0 = (wg % NT) * 64;
    const int frow = lane & 15;
    const int kb = (lane >> 4) * 16;
    char* cAs = (char*)As; char* cBs = (char*)Bs;

    f32x4 acc[4][2] = {};

    auto stage = [&](int buf, int k0) {             // 6 loads / thread
#pragma unroll
        for (int i = 0; i < 4; ++i) {               // A tile: 16 KB
            const int o = tid * 16 + i * 4096;
            const int row = o >> 7;
            const int cb = (o & 127) ^ ((row & 7) << 4);
            async16(A + (size_t)(m0 + row) * K + k0 + (cb >> 1),
                    cAs + buf * 16384 + o);
        }
#pragma unroll
        for (int i = 0; i < 2; ++i) {               // B tile: 8 KB
            const int o = tid * 16 + i * 4096;
            const int row = o >> 7;
            const int cb = (o & 127) ^ ((row & 7) << 4);
            async16(Bt + (size_t)(n0 + row) * K + k0 + (cb >> 1),
                    cBs + buf * 8192 + o);
        }
    };

    auto compute = [&](int buf) {
        char* lA = cAs + buf * 16384;
        char* lB = cBs + buf * 8192;
#pragma unroll
        for (int kk = 0; kk < 2; ++kk) {
            bf16x8 af[4], bfr[2];
#pragma unroll
            for (int m = 0; m < 4; ++m) {
                const int r = wr * 64 + m * 16 + frow;
                af[m] = *(const bf16x8*)(lA + ((r * 128 + kk * 64 + kb) ^ ((r & 7) << 4)));
            }
#pragma unroll
            for (int n = 0; n < 2; ++n) {
                const int r = wc * 32 + n * 16 + frow;
                bfr[n] = *(const bf16x8*)(lB + ((r * 128 + kk * 64 + kb) ^ ((r & 7) << 4)));
            }
#pragma unroll
            for (int m = 0; m < 4; ++m)
#pragma unroll
                for (int n = 0; n < 2; ++n)
                    acc[m][n] = __builtin_amdgcn_mfma_f32_16x16x32_bf16(
                        af[m], bfr[n], acc[m][n], 0, 0, 0);
        }
    };

    stage(0, 0);
    for (int t = 0; t < 16; ++t) {
        // buf (t+1)&1 was last read at t-1; barrier(t-1) protects overwrite.
        if (t < 15) { stage((t + 1) & 1, (t + 1) * 64); WAITVM(6); }
        else        { WAITVM(0); }
        __builtin_amdgcn_sched_barrier(0);
        compute(t & 1);
        __builtin_amdgcn_s_barrier();
    }

    const float sv = (EPI >= 2) ? *scal : 0.f;
#pragma unroll
    for (int m = 0; m < 4; ++m) {
#pragma unroll
        for (int n = 0; n < 2; ++n) {
#pragma unroll
            for (int r = 0; r < 4; ++r) {
                const int row = m0 + wr * 64 + m * 16 + (lane >> 4) * 4 + r;
                const int col = n0 + wc * 32 + n * 16 + frow;
                const size_t idx = (size_t)row * Ntot + col;
                float v = acc[m][n][r] + bias[col];
                if constexpr (EPI == 0) {
                    ((__bf16*)out)[idx] = (__bf16)v;
                } else if constexpr (EPI == 1) {
                    v = v > 0.f ? v : 0.2f * v;
                    ((__bf16*)out)[idx] = (__bf16)v;
                } else if constexpr (EPI == 2) {
                    ((__bf16*)out)[idx] = (__bf16)((float)aux[idx] + sv * v);
                } else {
                    ((float*)out)[idx] = (float)aux[idx] + sv * v;
                }
            }
        }
    }
}

// ---------------------------------------------------------------------------
// QKV GEMM: out[M][3072] = A @ Bt^T + bias.  Tile 128x128, 4 waves (2x2)
// each 64x64 (acc 4x4). 64 KB LDS dbuf, lb(256,2).
// Single-barrier loop: stage(next); WAITVM(8); compute(cur); barrier.
// ---------------------------------------------------------------------------
__global__ __launch_bounds__(256, 2) void gemm_qkv(
    const __bf16* __restrict__ A, const __bf16* __restrict__ Bt,
    const float* __restrict__ bias, __bf16* __restrict__ out)
{
    constexpr int K = D_;
    constexpr int NT = 24;                          // 3072 / 128
    constexpr int Ntot = 3 * D_;
    __shared__ __align__(16) __bf16 As[2][128][64]; // 32 KB
    __shared__ __align__(16) __bf16 Bs[2][128][64]; // 32 KB

    const int tid = threadIdx.x, lane = tid & 63, wid = tid >> 6;
    const int wr = wid >> 1, wc = wid & 1;
    const int cpx = (int)gridDim.x >> 3;            // 96
    const int bid = (int)blockIdx.x;
    const int wg = (bid & 7) * cpx + (bid >> 3);
    const int m0 = (wg / NT) * 128;
    const int n0 = (wg % NT) * 128;
    const int frow = lane & 15;
    const int kb = (lane >> 4) * 16;
    char* cAs = (char*)As; char* cBs = (char*)Bs;

    f32x4 acc[4][4] = {};

    auto stage = [&](int buf, int k0) {             // 8 loads / thread
#pragma unroll
        for (int i = 0; i < 4; ++i) {
            const int o = tid * 16 + i * 4096;
            const int row = o >> 7;
            const int cb = (o & 127) ^ ((row & 7) << 4);
            async16(A + (size_t)(m0 + row) * K + k0 + (cb >> 1),
                    cAs + buf * 16384 + o);
            async16(Bt + (size_t)(n0 + row) * K + k0 + (cb >> 1),
                    cBs + buf * 16384 + o);
        }
    };

    auto compute = [&](int buf) {
        char* lA = cAs + buf * 16384;
        char* lB = cBs + buf * 16384;
#pragma unroll
        for (int kk = 0; kk < 2; ++kk) {
            bf16x8 af[4], bfr[4];
#pragma unroll
            for (int m = 0; m < 4; ++m) {
                const int r = wr * 64 + m * 16 + frow;
                af[m] = *(const bf16x8*)(lA + ((r * 128 + kk * 64 + kb) ^ ((r & 7) << 4)));
            }
#pragma unroll
            for (int n = 0; n < 4; ++n) {
                const int r = wc * 64 + n * 16 + frow;
                bfr[n] = *(const bf16x8*)(lB + ((r * 128 + kk * 64 + kb) ^ ((r & 7) << 4)));
            }
#pragma unroll
            for (int m = 0; m < 4; ++m)
#pragma unroll
                for (int n = 0; n < 4; ++n)
                    acc[m][n] = __builtin_amdgcn_mfma_f32_16x16x32_bf16(
                        af[m], bfr[n], acc[m][n], 0, 0, 0);
        }
    };

    stage(0, 0);
    for (int t = 0; t < 16; ++t) {
        if (t < 15) { stage((t + 1) & 1, (t + 1) * 64); WAITVM(8); }
        else        { WAITVM(0); }
        __builtin_amdgcn_sched_barrier(0);
        compute(t & 1);
        __builtin_amdgcn_s_barrier();
    }

#pragma unroll
    for (int m = 0; m < 4; ++m) {
#pragma unroll
        for (int n = 0; n < 4; ++n) {
#pragma unroll
            for (int r = 0; r < 4; ++r) {
                const int row = m0 + wr * 64 + m * 16 + (lane >> 4) * 4 + r;
                const int col = n0 + wc * 64 + n * 16 + frow;
                out[(size_t)row * Ntot + col] = (__bf16)(acc[m][n][r] + bias[col]);
            }
        }
    }
}

// ---------------------------------------------------------------------------
// Fused attention (sigmoid*tanh on logits — no softmax). Same computeTile /
// lane mappings as the verified r7/r9 kernel; only the outer loop changes to
// the single-barrier counted-prefetch form (32 barriers per block, was 64).
// XCD-bijective 1D grid (1024 blocks), 4 waves x 16 q-rows, KVBLK=64 dbuf,
// swapped QK^T + packed b64 P-writes, wave-private Ps, setprio around MFMA.
// ---------------------------------------------------------------------------
__global__ __launch_bounds__(256, 4) void attn_k(
    const __bf16* __restrict__ Q, const __bf16* __restrict__ Kmat,
    const __bf16* __restrict__ VT, __bf16* __restrict__ CTX, int ld)
{
    __shared__ __align__(16) __bf16 Ks[2][64][64];  // 16 KB [buf][key][hd]
    __shared__ __align__(16) __bf16 Vs[2][64][64];  // 16 KB [buf][d][key]
    __shared__ __align__(16) __bf16 Ps[64][64];     //  8 KB [q][key]

    const int tid = threadIdx.x, wid = tid >> 6, lane = tid & 63;
    const int bid = (int)blockIdx.x;
    const int wg = (bid & 7) * 128 + (bid >> 3);    // 1024 blocks, bijective
    const int qt = wg & 31, h = (wg >> 5) & 15, b = wg >> 9;
    const int q0 = qt * 64;
    const int frow = lane & 15, g = lane >> 4;
    const int kg8 = g * 8, kb = g * 16;
    const int qrow = wid * 16 + frow;               // this lane's q row

    const __bf16* qbase = Q    + (size_t)(b * S_ + q0) * ld + h * 64;
    const __bf16* kbase = Kmat + (size_t)b * S_ * ld + h * 64;
    const __bf16* vbase = VT   + (size_t)(b * H_ + h) * 64 * S_;

    bf16x8 qf[2];
#pragma unroll
    for (int kk = 0; kk < 2; ++kk)
        qf[kk] = *(const bf16x8*)(qbase + (size_t)qrow * ld + kk * 32 + kg8);
    __builtin_amdgcn_sched_barrier(0);   // qf loads oldest in vmcnt queue

    f32x4 octx[4] = {};
    char* cKs = (char*)Ks; char* cVs = (char*)Vs; char* lPs = (char*)Ps;

    auto stageKV = [&](int buf, int kt) {           // 4 loads / thread
#pragma unroll
        for (int i = 0; i < 2; ++i) {
            const int o = tid * 16 + i * 4096;      // 0..8KB
            const int row = o >> 7;
            const int cb = (o & 127) ^ ((row & 7) << 4);
            async16(kbase + (size_t)(kt + row) * ld + (cb >> 1),
                    cKs + buf * 8192 + o);
            async16(vbase + (size_t)row * S_ + kt + (cb >> 1),
                    cVs + buf * 8192 + o);
        }
    };

    auto computeTile = [&](char* lKs, char* lVs) {
        // ---- S^T = K Q^T: lane holds P[key=16n+4g+r][q=qrow]
        f32x4 scc[4] = {};
        __builtin_amdgcn_s_setprio(1);
#pragma unroll
        for (int kk = 0; kk < 2; ++kk) {
            bf16x8 kf[4];
#pragma unroll
            for (int n = 0; n < 4; ++n) {
                const int r = n * 16 + frow;
                kf[n] = *(const bf16x8*)(lKs + ((r * 128 + kk * 64 + kb) ^ ((r & 7) << 4)));
            }
#pragma unroll
            for (int n = 0; n < 4; ++n)
                scc[n] = __builtin_amdgcn_mfma_f32_16x16x32_bf16(
                    kf[n], qf[kk], scc[n], 0, 0, 0);
        }
        __builtin_amdgcn_s_setprio(0);
        // ---- activation + packed b64 P-write (4 consecutive keys/write)
#pragma unroll
        for (int n = 0; n < 4; ++n) {
            bf16x4 pw;
#pragma unroll
            for (int r = 0; r < 4; ++r) pw[r] = (__bf16)actf(scc[n][r]);
            *(bf16x4*)(lPs + ((qrow * 128 + n * 32 + g * 8) ^ ((qrow & 7) << 4))) = pw;
        }
        // ---- ctx += P @ V  (wave-private P rows: no barrier)
        __builtin_amdgcn_s_setprio(1);
#pragma unroll
        for (int ks = 0; ks < 2; ++ks) {
            bf16x8 pf = *(const bf16x8*)(lPs +
                ((qrow * 128 + ks * 64 + kb) ^ ((qrow & 7) << 4)));
            bf16x8 vf[4];
#pragma unroll
            for (int nd = 0; nd < 4; ++nd) {
                const int rd = nd * 16 + frow;
                vf[nd] = *(const bf16x8*)(lVs + ((rd * 128 + ks * 64 + kb) ^ ((rd & 7) << 4)));
            }
#pragma unroll
            for (int nd = 0; nd < 4; ++nd)
                octx[nd] = __builtin_amdgcn_mfma_f32_16x16x32_bf16(
                    pf, vf[nd], octx[nd], 0, 0, 0);
        }
        __builtin_amdgcn_s_setprio(0);
    };

    stageKV(0, 0);
    for (int t = 0; t < 32; ++t) {                  // 32 key-tiles of 64
        // buf (t+1)&1 last read at t-1; barrier(t-1) protects overwrite.
        if (t < 31) { stageKV((t + 1) & 1, (t + 1) * 64); WAITVM(4); }
        else        { WAITVM(0); }
        __builtin_amdgcn_sched_barrier(0);
        computeTile(cKs + (t & 1) * 8192, cVs + (t & 1) * 8192);
        __builtin_amdgcn_s_barrier();
    }

#pragma unroll
    for (int nd = 0; nd < 4; ++nd)
#pragma unroll
        for (int r = 0; r < 4; ++r) {
            const int row = q0 + wid * 16 + g * 4 + r;
            const int col = h * 64 + nd * 16 + frow;
            CTX[(size_t)(b * S_ + row) * D_ + col] = (__bf16)octx[nd][r];
        }
}

// ---------------------------------------------------------------------------
struct WPack { const float* w[7]; };

__global__ __launch_bounds__(256) void conv_transpose_w(WPack p, __bf16* out) {
    __shared__ float t[32][33];
    const float* W = p.w[blockIdx.z];
    __bf16* o = out + (size_t)blockIdx.z * D_ * D_;
    const int c0 = blockIdx.x * 32, r0 = blockIdx.y * 32;
    const int tx = threadIdx.x, ty = threadIdx.y;
#pragma unroll
    for (int i = 0; i < 4; ++i)
        t[ty + i * 8][tx] = W[(size_t)(r0 + ty + i * 8) * D_ + c0 + tx];
    __syncthreads();
#pragma unroll
    for (int i = 0; i < 4; ++i)
        o[(size_t)(c0 + ty + i * 8) * D_ + r0 + tx] = (__bf16)t[tx][ty + i * 8];
}

__global__ __launch_bounds__(256) void conv_bf16(
    const float* __restrict__ in, __bf16* __restrict__ out, int n4)
{
    const int i = blockIdx.x * blockDim.x + threadIdx.x;
    if (i < n4) {
        f32x4 v = ((const f32x4*)in)[i];
        bf16x4 o;
        o[0] = (__bf16)v[0]; o[1] = (__bf16)v[1];
        o[2] = (__bf16)v[2]; o[3] = (__bf16)v[3];
        ((bf16x4*)out)[i] = o;
    }
}

__global__ __launch_bounds__(256) void bcat_k(
    const float* __restrict__ bq, const float* __restrict__ bk,
    const float* __restrict__ bv, float* __restrict__ o)
{
    const int i = blockIdx.x * 256 + threadIdx.x;   // 0..3071
    o[i] = i < 1024 ? bq[i] : (i < 2048 ? bk[i - 1024] : bv[i - 2048]);
}

// V rows of QKV [B*S][ld] -> VT[(b*D + col)][S]
__global__ __launch_bounds__(256) void transpose_v(
    const __bf16* __restrict__ V, __bf16* __restrict__ VT, int ld)
{
    __shared__ __bf16 t[32][33];
    const int s0 = blockIdx.x * 32, c0 = blockIdx.y * 32, b = blockIdx.z;
    const int tx = threadIdx.x, ty = threadIdx.y;
#pragma unroll
    for (int i = 0; i < 4; ++i)
        t[ty + i * 8][tx] = V[(size_t)(b * S_ + s0 + ty + i * 8) * ld + c0 + tx];
    __syncthreads();
#pragma unroll
    for (int i = 0; i < 4; ++i)
        VT[(size_t)(b * D_ + c0 + ty + i * 8) * S_ + s0 + tx] = t[tx][ty + i * 8];
}

// ---------------------------------------------------------------------------
extern "C" void kernel_launch(void* const* d_in, const int* in_sizes, int n_in,
                              void* d_out, int out_size, void* d_ws, size_t ws_size,
                              hipStream_t stream) {
    const float* x    = (const float*)d_in[0];
    const float* W_in = (const float*)d_in[1];
    const float* b_in = (const float*)d_in[2];
    const float* Wq   = (const float*)d_in[3];
    const float* bq   = (const float*)d_in[4];
    const float* Wk   = (const float*)d_in[5];
    const float* bk   = (const float*)d_in[6];
    const float* Wv   = (const float*)d_in[7];
    const float* bv   = (const float*)d_in[8];
    const float* Wo   = (const float*)d_in[9];
    const float* bo   = (const float*)d_in[10];
    const float* W1   = (const float*)d_in[11];
    const float* b1   = (const float*)d_in[12];
    const float* W2   = (const float*)d_in[13];
    const float* b2   = (const float*)d_in[14];
    const float* s_att = (const float*)d_in[15];
    const float* s_ff  = (const float*)d_in[16];

    char* ws = (char*)d_ws;
    const size_t WB = (size_t)D_ * D_ * 2;       // 2 MB / bf16 weight
    const size_t MB = (size_t)M_ * D_ * 2;       // 8 MB / bf16 activation
    __bf16* WT   = (__bf16*)(ws);                           // 14 MB
    __bf16* Hb   = (__bf16*)(ws + 7 * WB);                  // 8 MB
    __bf16* QKVb = (__bf16*)(ws + 7 * WB + MB);             // 24 MB
    __bf16* VTb  = (__bf16*)(ws + 7 * WB + 4 * MB);         // 8 MB
    __bf16* Xb   = (__bf16*)(ws + 7 * WB + 5 * MB);         // 8 MB
    float*  bcat = (float*)VTb;       // alias: bcat dead before VTb written
    __bf16* CTXb = Xb;                // x dead after first GEMM
    __bf16* LATb = QKVb;              // qkv dead after attention
    __bf16* FF1b = QKVb + (size_t)M_ * D_;
    auto WTi = [&](int i) { return WT + (size_t)i * D_ * D_; };

    WPack wp;
    wp.w[0] = W_in; wp.w[1] = Wq; wp.w[2] = Wk; wp.w[3] = Wv;
    wp.w[4] = Wo;   wp.w[5] = W1; wp.w[6] = W2;
    conv_transpose_w<<<dim3(32, 32, 7), dim3(32, 8), 0, stream>>>(wp, WT);
    conv_bf16<<<dim3(4096), dim3(256), 0, stream>>>(x, Xb, (M_ * D_) / 4);
    bcat_k<<<dim3(12), dim3(256), 0, stream>>>(bq, bk, bv, bcat);

    // h = x @ W_in + b_in            (32 m x 16 n = 512 blocks)
    gemm_k<0, 16><<<dim3(512), dim3(256), 0, stream>>>(
        Xb, WTi(0), b_in, nullptr, nullptr, Hb);
    // qkv = h @ [Wq|Wk|Wv] + bcat    (N=3072: 32 x 24 = 768 blocks, 128x128)
    gemm_qkv<<<dim3(768), dim3(256), 0, stream>>>(Hb, WTi(1), bcat, QKVb);
    transpose_v<<<dim3(64, 32, 2), dim3(32, 8), 0, stream>>>(
        QKVb + 2 * D_, VTb, 3 * D_);
    attn_k<<<dim3(1024), dim3(256), 0, stream>>>(
        QKVb, QKVb + D_, VTb, CTXb, 3 * D_);
    // latent = h + s_att * (ctx @ Wo + bo)
    gemm_k<2, 16><<<dim3(512), dim3(256), 0, stream>>>(
        CTXb, WTi(4), bo, Hb, s_att, LATb);
    // ff1 = leaky_relu(latent @ W1 + b1)
    gemm_k<1, 16><<<dim3(512), dim3(256), 0, stream>>>(
        LATb, WTi(5), b1, nullptr, nullptr, FF1b);
    // out = latent + s_ff * (ff1 @ W2 + b2)  (f32)
    gemm_k<3, 16><<<dim3(512), dim3(256), 0, stream>>>(
        FF1b, WTi(6), b2, LATb, s_ff, d_out);
}